// Round 6
// baseline (479.085 us; speedup 1.0000x reference)
//
#include <hip/hip_runtime.h>
#include <math.h>

#define B_   8
#define C_   256
#define HW_  4096
#define N_   32768   // B_*HW_
#define M_   2024
#define MP_  2048    // M padded to multiple of 64
#define CH_  64
#define NCHUNK (MP_ / 64)  // 32
#define INV_TEMP 33.333333333333336f
#define NEPS 1e-12f

typedef __attribute__((ext_vector_type(8))) short short8;   // 8 x bf16 (4 VGPRs)
typedef __attribute__((ext_vector_type(4))) float floatx4;  // MFMA accumulator

__device__ __forceinline__ float wred64(float s) {
#pragma unroll
  for (int off = 32; off > 0; off >>= 1) s += __shfl_xor(s, off, 64);
  return s;
}

__device__ __forceinline__ unsigned short f2bf(float f) {
  union { float f; unsigned u; } v; v.f = f;
  unsigned r = v.u + 0x7FFFu + ((v.u >> 16) & 1u);  // RNE, finite inputs only
  return (unsigned short)(r >> 16);
}
__device__ __forceinline__ float bf2f(unsigned short b) {
  union { unsigned u; float f; } v; v.u = ((unsigned)b) << 16; return v.f;
}

// raw workgroup barrier: orders LDS only (lgkmcnt), does NOT drain vmcnt —
// global loads stay in flight and compiler keeps them pipelined.
__device__ __forceinline__ void barrier_lds_only() {
  asm volatile("s_waitcnt lgkmcnt(0)\n\ts_barrier" ::: "memory");
}

// ---- normalize memory rows -> memS (MFMA B-frag order) + membT [C][MP] ----
// memS element (m, c): unit = ((m>>6)*32 + (c>>5)*4 + ((c>>3)&3))*64 + (m&63),
// u16 index = unit*8 + (c&7). Reader (wave quad q, lane lm) gets exact B-frags
// with coalesced b128 loads. Block 64 additionally rearranges the gate weights:
// wgB in the same B-frag order (col=h, k=c), gmeta = [b1(2x64) | w2(2x64) | b2(2)].
__global__ __launch_bounds__(256) void norm_mem_kernel(
    const float* __restrict__ fg, const float* __restrict__ bg,
    unsigned short* __restrict__ fgS, unsigned short* __restrict__ bgS,
    unsigned short* __restrict__ fgT, unsigned short* __restrict__ bgT,
    const float* __restrict__ w1f, const float* __restrict__ b1f,
    const float* __restrict__ w2f, const float* __restrict__ b2f,
    const float* __restrict__ w1b, const float* __restrict__ b1b,
    const float* __restrict__ w2b, const float* __restrict__ b2b,
    unsigned short* __restrict__ wgB, float* __restrict__ gmeta) {
  int bid = blockIdx.x;
  int t = threadIdx.x;
  if (bid >= 64) {  // ---- gate-weight prep ----
    for (int u = t; u < 4096; u += 256) {
      int gate = u >> 11, ct = (u >> 9) & 3, kb = (u >> 6) & 7, l = u & 63;
      const float* w1 = gate ? w1b : w1f;
      int h = ct * 16 + (l & 15);
      int cbase = kb * 32 + (l >> 4) * 8;
#pragma unroll
      for (int j = 0; j < 8; ++j)
        wgB[(size_t)u * 8 + j] = f2bf(w1[(size_t)(cbase + j) * CH_ + h]);
    }
    if (t < 128) {
      int gate = t >> 6, h = t & 63;
      gmeta[t]       = gate ? b1b[h] : b1f[h];
      gmeta[128 + t] = gate ? w2b[h] : w2f[h];
    }
    if (t < 2) gmeta[256 + t] = t ? b2b[0] : b2f[0];
    return;
  }
  __shared__ unsigned short tile[64][258];
  const float* src; unsigned short *ms, *mt; int r0;
  if (bid < 32) { src = fg; ms = fgS; mt = fgT; r0 = bid * 64; }
  else          { src = bg; ms = bgS; mt = bgT; r0 = (bid - 32) * 64; }
  int rr = t >> 2, c4 = t & 3;  // row r0+rr, channel quarter c4
  int row = r0 + rr;
  int chunk = r0 >> 6;
  float v[64];
  float s = 0.f;
  if (row < M_) {
    const float4* p = (const float4*)(src + (size_t)row * C_ + c4 * 64);
#pragma unroll
    for (int i = 0; i < 16; ++i) {
      float4 q = p[i];
      v[i * 4 + 0] = q.x; v[i * 4 + 1] = q.y; v[i * 4 + 2] = q.z; v[i * 4 + 3] = q.w;
      s += q.x * q.x + q.y * q.y + q.z * q.z + q.w * q.w;
    }
  } else {
#pragma unroll
    for (int i = 0; i < 64; ++i) v[i] = 0.f;  // zero padding rows
  }
  s += __shfl_xor(s, 1, 64);
  s += __shfl_xor(s, 2, 64);
  float inv = (row < M_) ? 1.0f / fmaxf(sqrtf(s), NEPS) : 0.f;
#pragma unroll
  for (int i = 0; i < 16; ++i) {
    int c = c4 * 64 + i * 4;
    ushort4 o;
    o.x = f2bf(v[i * 4 + 0] * inv); o.y = f2bf(v[i * 4 + 1] * inv);
    o.z = f2bf(v[i * 4 + 2] * inv); o.w = f2bf(v[i * 4 + 3] * inv);
    int unit = (chunk * 32 + (c >> 5) * 4 + ((c >> 3) & 3)) * 64 + rr;
    *(ushort4*)&ms[(size_t)unit * 8 + (c & 7)] = o;
    *(ushort4*)&tile[rr][c] = o;
  }
  __syncthreads();
  int m = t & 63, cw = t >> 6;
#pragma unroll 8
  for (int j = 0; j < 64; ++j) {
    int c = cw * 64 + j;
    mt[(size_t)c * MP_ + r0 + m] = tile[m][c];
  }
}

// ---- fused per-pixel inv-norm + xnb bf16 [N,C] build (one feats pass) ----
__global__ __launch_bounds__(256) void prep_x_kernel(
    const float* __restrict__ feats, float* __restrict__ invn,
    unsigned short* __restrict__ xnb) {
  __shared__ unsigned short tileb[256][66];
  __shared__ float part[4][64];
  __shared__ float invs[64];
  int t = threadIdx.x, hwl = t & 63, cw = t >> 6;
  int n0 = blockIdx.x * 64;
  int b = n0 >> 12, hw0 = n0 & 4095;
  const float* p = feats + (size_t)b * C_ * HW_ + hw0 + hwl;
  float s = 0.f;
#pragma unroll 8
  for (int i = 0; i < 64; ++i) {
    int c = cw * 64 + i;
    float v = p[(size_t)c * HW_];
    s += v * v;
    tileb[c][hwl] = f2bf(v);
  }
  part[cw][hwl] = s;
  __syncthreads();
  if (t < 64) {
    float tot = part[0][t] + part[1][t] + part[2][t] + part[3][t];
    float inv = 1.0f / fmaxf(sqrtf(tot), NEPS);
    invn[n0 + t] = inv;
    invs[t] = inv;
  }
  __syncthreads();
  int px = t >> 2, q = t & 3;
  float iv = invs[px];
  unsigned short* xp = xnb + (size_t)(n0 + px) * C_;
#pragma unroll
  for (int blk = 0; blk < 8; ++blk) {
    int cb = blk * 4 + q;  // 4 q-lanes -> 64 B contiguous stores
    short8 o;
#pragma unroll
    for (int j = 0; j < 8; ++j)
      o[j] = (short)f2bf(bf2f(tileb[cb * 8 + j][px]) * iv);
    *(short8*)&xp[cb * 8] = o;
  }
}

// ---------------- fused MFMA flash attention v5 ----------------
// 64 pixels/block, 8 waves, 2 blocks/CU. No LDS staging: S-phase B-frags read
// directly from global memS (frag-order, coalesced b128, L1/L2-resident);
// ONE lgkm-only barrier per chunk (P double-buffer handoff; 2-chunk
// anti-dependence distance makes buffer reuse safe). Gate MLPs fused via
// MFMA reusing the A-frags (wave (rg,mh): gate mh, rows 16rg..+16).
__global__ __launch_bounds__(512, 4) void flash_fused_kernel(
    const unsigned short* __restrict__ xnb,
    const unsigned short* __restrict__ fgS, const unsigned short* __restrict__ fgT,
    const unsigned short* __restrict__ bgS, const unsigned short* __restrict__ bgT,
    const unsigned short* __restrict__ wgB, const float* __restrict__ gmeta,
    const float* __restrict__ feats, const float* __restrict__ invn,
    float* __restrict__ out) {
  __shared__ __align__(16) char smem[18176];
  unsigned short* Pbuf0 = (unsigned short*)smem;            // 8 KB, unit=(m>>3)*64+prow
  unsigned short* Pbuf1 = (unsigned short*)(smem + 8192);   // 8 KB
  float* trans  = (float*)smem;                             // [64][67] f32, aliases Pbufs
  float* rowsum = (float*)(smem + 17152);                   // [64]
  float* comb   = (float*)(smem + 17408);                   // [64]
  float* gbuf   = (float*)(smem + 17664);                   // [2][64] gates

  int t = threadIdx.x;
  int w = t >> 6, l = t & 63;
  int lm = l & 15, quad = l >> 4;
  int rg = w & 3, mh = w >> 2;
  int row0 = blockIdx.x * 64;

  // A-frags: rows row0 + 16*rg + lm, k = kb*32 + quad*8 + j
  short8 afrag[8];
  {
    const unsigned short* ap = xnb + (size_t)(row0 + 16 * rg + lm) * C_ + quad * 8;
#pragma unroll
    for (int kb = 0; kb < 8; ++kb)
      afrag[kb] = *(const short8*)(ap + kb * 32);
  }

  // ---- gates via MFMA (once per block): wave (rg,mh) -> gate mh, 16 rows ----
  {
    floatx4 accH[4];
#pragma unroll
    for (int ct = 0; ct < 4; ++ct) accH[ct] = (floatx4){0.f, 0.f, 0.f, 0.f};
#pragma unroll
    for (int ct = 0; ct < 4; ++ct)
#pragma unroll
      for (int kb = 0; kb < 8; ++kb) {
        short8 wf = *(const short8*)&wgB[(size_t)((((mh * 4 + ct) * 8) + kb) * 64 + l) * 8];
        accH[ct] = __builtin_amdgcn_mfma_f32_16x16x32_bf16(afrag[kb], wf, accH[ct], 0, 0, 0);
      }
    float part[4] = {0.f, 0.f, 0.f, 0.f};
#pragma unroll
    for (int ct = 0; ct < 4; ++ct) {
      float b1v = gmeta[mh * 64 + ct * 16 + lm];
      float w2v = gmeta[128 + mh * 64 + ct * 16 + lm];
#pragma unroll
      for (int r = 0; r < 4; ++r)
        part[r] += fmaxf(accH[ct][r] + b1v, 0.f) * w2v;
    }
#pragma unroll
    for (int off = 1; off < 16; off <<= 1)
#pragma unroll
      for (int r = 0; r < 4; ++r) part[r] += __shfl_xor(part[r], off, 64);
    float b2v = gmeta[256 + mh];
    if (lm == 0) {
#pragma unroll
      for (int r = 0; r < 4; ++r)
        gbuf[mh * 64 + 16 * rg + quad * 4 + r] =
            1.f / (1.f + __expf(-(part[r] + b2v)));
    }
  }

  int bb = row0 >> 12, hw0 = row0 & 4095;
  float iv = invn[row0 + l];
  size_t ob = (size_t)bb * (size_t)C_ * HW_ + hw0 + l;

#pragma unroll 1
  for (int pass = 0; pass < 2; ++pass) {
    const unsigned short* memS  = pass ? bgS : fgS;
    const unsigned short* membT = pass ? bgT : fgT;

    floatx4 accO[4][2];
#pragma unroll
    for (int rt = 0; rt < 4; ++rt)
#pragma unroll
      for (int ct = 0; ct < 2; ++ct) accO[rt][ct] = (floatx4){0.f, 0.f, 0.f, 0.f};
    float rs[4] = {0.f, 0.f, 0.f, 0.f};
    if (t < 64) rowsum[t] = 0.f;  // ordered before the pass-end atomics by barriers

#pragma unroll 1
    for (int mc = 0; mc < NCHUNK; ++mc) {
      // PV B-frags (global, used after the barrier -> long prefetch distance)
      short8 bfT[2][2];
#pragma unroll
      for (int ct = 0; ct < 2; ++ct) {
        const unsigned short* tp =
            membT + (size_t)(w * 32 + ct * 16 + lm) * MP_ + mc * 64 + quad * 8;
        bfT[ct][0] = *(const short8*)(tp);
        bfT[ct][1] = *(const short8*)(tp + 32);
      }

      // ---- S = Q @ mem^T: B-frags straight from global memS (frag order) ----
      floatx4 accS[2];
      accS[0] = (floatx4){0.f, 0.f, 0.f, 0.f};
      accS[1] = (floatx4){0.f, 0.f, 0.f, 0.f};
      {
        const unsigned short* sp = memS + (size_t)mc * 16384;
#pragma unroll
        for (int mt2 = 0; mt2 < 2; ++mt2) {
          int mrow = mh * 32 + mt2 * 16 + lm;
#pragma unroll
          for (int kb = 0; kb < 8; ++kb) {
            short8 bf = *(const short8*)&sp[(size_t)((kb * 4 + quad) * 64 + mrow) * 8];
            accS[mt2] = __builtin_amdgcn_mfma_f32_16x16x32_bf16(afrag[kb], bf, accS[mt2], 0, 0, 0);
          }
        }
      }

      // ---- P = exp(S/T) bf16 (unnormalized; |logit|<=33.3) -> LDS frag order ----
      unsigned short* P = (mc & 1) ? Pbuf1 : Pbuf0;
#pragma unroll
      for (int mt2 = 0; mt2 < 2; ++mt2) {
        int m = mh * 32 + mt2 * 16 + lm;
        bool valid = (mc * 64 + m < M_);
        int g = m >> 3;  // = mh*4 + mt2*2 + (lm>>3)
#pragma unroll
        for (int r = 0; r < 4; ++r) {
          float pv = valid ? __expf(accS[mt2][r] * INV_TEMP) : 0.f;
          rs[r] += pv;
          P[(size_t)(g * 64 + 16 * rg + quad * 4 + r) * 8 + (m & 7)] = f2bf(pv);
        }
      }
      barrier_lds_only();  // single barrier/chunk: P visible, prev P-reads done

      // ---- O += P @ mem (this wave's 32-wide C-slice) ----
#pragma unroll
      for (int rt = 0; rt < 4; ++rt) {
        short8 pf0 = *(const short8*)&P[(size_t)((0 + quad) * 64 + rt * 16 + lm) * 8];
        short8 pf1 = *(const short8*)&P[(size_t)((4 + quad) * 64 + rt * 16 + lm) * 8];
#pragma unroll
        for (int ct = 0; ct < 2; ++ct) {
          accO[rt][ct] = __builtin_amdgcn_mfma_f32_16x16x32_bf16(pf0, bfT[ct][0], accO[rt][ct], 0, 0, 0);
          accO[rt][ct] = __builtin_amdgcn_mfma_f32_16x16x32_bf16(pf1, bfT[ct][1], accO[rt][ct], 0, 0, 0);
        }
      }
    }

    // ---- rowsum: intra-wave shuffle over lm, cross-wave LDS atomic ----
#pragma unroll
    for (int off = 1; off < 16; off <<= 1)
#pragma unroll
      for (int r = 0; r < 4; ++r) rs[r] += __shfl_xor(rs[r], off, 64);
    if (lm == 0) {
#pragma unroll
      for (int r = 0; r < 4; ++r) atomicAdd(&rowsum[16 * rg + quad * 4 + r], rs[r]);
    }
    __syncthreads();
    if (t < 64) comb[t] = gbuf[pass * 64 + t] / rowsum[t];
    __syncthreads();

    // ---- epilogue via LDS transpose (trans aliases P buffers) ----
#pragma unroll 1
    for (int cg2 = 0; cg2 < 4; ++cg2) {
      if ((w >> 1) == cg2) {
#pragma unroll
        for (int rt = 0; rt < 4; ++rt)
#pragma unroll
          for (int r = 0; r < 4; ++r) {
            float cf = comb[16 * rt + quad * 4 + r];
#pragma unroll
            for (int ct = 0; ct < 2; ++ct)
              trans[(16 * rt + quad * 4 + r) * 67 + (w & 1) * 32 + ct * 16 + lm] =
                  cf * accO[rt][ct][r];
          }
      }
      __syncthreads();
      if (pass == 0) {
#pragma unroll
        for (int i = 0; i < 8; ++i) {
          int cl = w * 8 + i;
          int cg = cg2 * 64 + cl;
          out[ob + (size_t)cg * HW_] = trans[l * 67 + cl];  // out = alpha_f * O_f
        }
      } else {
#pragma unroll
        for (int i = 0; i < 8; ++i) {
          int cl = w * 8 + i;
          int cg = cg2 * 64 + cl;
          size_t a = ob + (size_t)cg * HW_;
          out[a] = feats[a] * iv + out[a] - trans[l * 67 + cl];
        }
      }
      __syncthreads();
    }
  }
}

extern "C" void kernel_launch(void* const* d_in, const int* in_sizes, int n_in,
                              void* d_out, int out_size, void* d_ws, size_t ws_size,
                              hipStream_t stream) {
  const float* feats = (const float*)d_in[0];
  const float* fg    = (const float*)d_in[1];
  const float* bg    = (const float*)d_in[2];
  const float* w1f   = (const float*)d_in[3];
  const float* b1f   = (const float*)d_in[4];
  const float* w2f   = (const float*)d_in[5];
  const float* b2f   = (const float*)d_in[6];
  const float* w1b   = (const float*)d_in[7];
  const float* b1b   = (const float*)d_in[8];
  const float* w2b   = (const float*)d_in[9];
  const float* b2b   = (const float*)d_in[10];
  float* out = (float*)d_out;

  char* ws = (char*)d_ws;
  unsigned short* xnb = (unsigned short*)ws;                 // N_*C_ bf16
  unsigned short* fgS = xnb + (size_t)N_ * C_;               // MP_*C_ (frag order)
  unsigned short* bgS = fgS + (size_t)MP_ * C_;
  unsigned short* fgT = bgS + (size_t)MP_ * C_;              // C_*MP_
  unsigned short* bgT = fgT + (size_t)C_ * MP_;
  unsigned short* wgB = bgT + (size_t)C_ * MP_;              // 2*C_*CH_ (frag order)
  float* gmeta = (float*)(wgB + 2 * C_ * CH_);               // 258
  float* invn  = gmeta + 272;                                // N_

  norm_mem_kernel<<<65, 256, 0, stream>>>(fg, bg, fgS, bgS, fgT, bgT,
                                          w1f, b1f, w2f, b2f,
                                          w1b, b1b, w2b, b2b, wgB, gmeta);
  prep_x_kernel<<<N_ / 64, 256, 0, stream>>>(feats, invn, xnb);
  flash_fused_kernel<<<N_ / 64, 512, 0, stream>>>(
      xnb, fgS, fgT, bgS, bgT, wgB, gmeta, feats, invn, out);
}